// Round 1
// baseline (6252.575 us; speedup 1.0000x reference)
//
#include <hip/hip_runtime.h>

// LSTM: B=64, T=512, D=1024, H=1024.
// Strategy:
//   prep_ew:   xs f32->f16, h0 f32->f16 (hbuf slot 0), zero flags
//   transpose: Wx,Wh [1024x4096] f32 -> [4096x1024] f16 (B^T layout, k-contiguous)
//   gemm1:     xproj = xs@Wx, f16 MFMA 128x128 tiles, out rows t*64+b, f16
//   rec:       persistent 64 wgs (1/CU), Wh^T slice in LDS, c in regs,
//              per-slice flag sync, depth-T h history (agent atomic stores)

typedef _Float16 half8 __attribute__((ext_vector_type(8)));
typedef float floatx4 __attribute__((ext_vector_type(4)));

#define T_DIM 512
#define B_DIM 64
#define H_DIM 1024
#define FOURH 4096

__device__ __forceinline__ void gll16(const void* g, void* l) {
  __builtin_amdgcn_global_load_lds(
      (const __attribute__((address_space(1))) unsigned int*)g,
      (__attribute__((address_space(3))) unsigned int*)l, 16, 0, 0);
}

__device__ __forceinline__ float sigm(float x) { return 1.f / (1.f + __expf(-x)); }
__device__ __forceinline__ float tanhfast(float x) { return 1.f - 2.f / (__expf(2.f * x) + 1.f); }

// ---------------- prep: convert xs, h0; zero flags ----------------
// groups of 8 elems: xs 4194304 groups, h0 8192 groups, flags 64 singles
__global__ void prep_ew(const float* __restrict__ xs, const float* __restrict__ h0,
                        _Float16* __restrict__ xs16, _Float16* __restrict__ hb0,
                        int* __restrict__ flags) {
  long gid = (long)blockIdx.x * blockDim.x + threadIdx.x;
  if (gid < 4194304) {
    const float4* p = (const float4*)xs + gid * 2;
    float4 u = p[0], w = p[1];
    half8 o;
    o[0] = (_Float16)u.x; o[1] = (_Float16)u.y; o[2] = (_Float16)u.z; o[3] = (_Float16)u.w;
    o[4] = (_Float16)w.x; o[5] = (_Float16)w.y; o[6] = (_Float16)w.z; o[7] = (_Float16)w.w;
    *(half8*)(xs16 + gid * 8) = o;
  } else if (gid < 4202496) {
    long j = gid - 4194304;
    const float4* p = (const float4*)h0 + j * 2;
    float4 u = p[0], w = p[1];
    half8 o;
    o[0] = (_Float16)u.x; o[1] = (_Float16)u.y; o[2] = (_Float16)u.z; o[3] = (_Float16)u.w;
    o[4] = (_Float16)w.x; o[5] = (_Float16)w.y; o[6] = (_Float16)w.z; o[7] = (_Float16)w.w;
    *(half8*)(hb0 + j * 8) = o;
  } else if (gid < 4202560) {
    flags[gid - 4202496] = 0;
  }
}

// ---------------- transpose [1024][4096] f32 -> [4096][1024] f16 ----------------
__global__ void transpose_k(const float* __restrict__ in, _Float16* __restrict__ outp) {
  __shared__ float s[32][33];
  int bx = blockIdx.x * 32, by = blockIdx.y * 32;
  int tx = threadIdx.x, ty = threadIdx.y;
#pragma unroll
  for (int k = 0; k < 32; k += 8)
    s[ty + k][tx] = in[(long)(by + ty + k) * 4096 + bx + tx];
  __syncthreads();
#pragma unroll
  for (int k = 0; k < 32; k += 8)
    outp[(long)(bx + ty + k) * 1024 + by + tx] = (_Float16)s[tx][ty + k];
}

// ---------------- gemm1: xproj[t*64+b][j] = sum_k xs16[b*512+t][k] * Wxt[j][k] ----------------
// 128x128 tile, 4 waves (2x2), BK=32, fragment-order LDS, global_load_lds 16B.
__global__ __launch_bounds__(256) void gemm1(const _Float16* __restrict__ A,
                                             const _Float16* __restrict__ Bt,
                                             _Float16* __restrict__ C) {
  __shared__ _Float16 sA[4096], sB[4096];
  const int tid = threadIdx.x;
  const int w = tid >> 6, l = tid & 63, li = l & 15, q = l >> 4;
  const int wr = w >> 1, wc = w & 1;
  const int m0 = blockIdx.y * 128, n0 = blockIdx.x * 128;
  floatx4 acc[4][4] = {};
  const _Float16* gA0 = A + (long)(m0 + (w * 16 + li)) * 1024 + q * 8;
  const _Float16* gA1 = A + (long)(m0 + ((4 + w) * 16 + li)) * 1024 + q * 8;
  const _Float16* gB0 = Bt + (long)(n0 + (w * 16 + li)) * 1024 + q * 8;
  const _Float16* gB1 = Bt + (long)(n0 + ((4 + w) * 16 + li)) * 1024 + q * 8;
  _Float16* lA0 = sA + (w * 64) * 8;
  _Float16* lA1 = sA + (256 + w * 64) * 8;
  _Float16* lB0 = sB + (w * 64) * 8;
  _Float16* lB1 = sB + (256 + w * 64) * 8;
  for (int k0 = 0; k0 < 1024; k0 += 32) {
    __syncthreads();
    gll16(gA0 + k0, lA0);
    gll16(gA1 + k0, lA1);
    gll16(gB0 + k0, lB0);
    gll16(gB1 + k0, lB1);
    __syncthreads();  // compiler drains vmcnt before s_barrier -> LDS data ready
    half8 af[4], bf[4];
    const half8* pA = (const half8*)sA;
    const half8* pB = (const half8*)sB;
#pragma unroll
    for (int i = 0; i < 4; i++) af[i] = pA[(wr * 4 + i) * 64 + l];
#pragma unroll
    for (int j = 0; j < 4; j++) bf[j] = pB[(wc * 4 + j) * 64 + l];
#pragma unroll
    for (int i = 0; i < 4; i++)
#pragma unroll
      for (int j = 0; j < 4; j++)
        acc[i][j] = __builtin_amdgcn_mfma_f32_16x16x32_f16(af[i], bf[j], acc[i][j], 0, 0, 0);
  }
  // epilogue: row m=b*512+t -> out row t*64+b (time-major for the scan)
#pragma unroll
  for (int i = 0; i < 4; i++) {
#pragma unroll
    for (int r = 0; r < 4; r++) {
      int m = m0 + wr * 64 + i * 16 + q * 4 + r;
      long orow = (long)(m & 511) * 64 + (m >> 9);
#pragma unroll
      for (int j = 0; j < 4; j++) {
        int gn = n0 + wc * 64 + j * 16 + li;
        C[orow * 4096 + gn] = (_Float16)acc[i][j][r];
      }
    }
  }
}

// ---------------- rec: persistent scan ----------------
// 64 wgs x 128 thr. wg w owns h-cols [w*16, w*16+16) i.e. gate cols {g*1024+w*16+kc}.
// Wave v covers batches [v*32, v*32+32) as 2 m-frags; 4 gate n-frags each.
__global__ __launch_bounds__(128, 1) void rec(const _Float16* __restrict__ xproj,
                                              const _Float16* __restrict__ Wht,
                                              const float* __restrict__ bias,
                                              const float* __restrict__ c0,
                                              _Float16* __restrict__ hbuf,
                                              int* __restrict__ flags,
                                              float* __restrict__ out) {
  __shared__ _Float16 sW[65536];  // [g(4)][kk(32)][lane(64)][8] = 128 KB, frag order
  __shared__ _Float16 sXp[4096];  // [c(512)][8] = 8 KB, c = g*128 + b*2 + hh
  const int tid = threadIdx.x;
  const int wgid = blockIdx.x;  // 0..63
  const int v = tid >> 6;       // wave 0/1
  const int l = tid & 63, li = l & 15, q = l >> 4;
  const int ks = wgid * 16;

  // stage Wh^T slice into LDS (once): 8192 chunks of 16B
#pragma unroll 4
  for (int i = 0; i < 64; i++) {
    int c = i * 128 + tid;
    int g = c >> 11, kk = (c >> 6) & 31;
    gll16(Wht + (long)((g << 10) + ks + li) * 1024 + kk * 32 + q * 8, sW + (long)(c - l) * 8);
  }
  float creg[2][4];
#pragma unroll
  for (int a = 0; a < 2; a++)
#pragma unroll
    for (int r = 0; r < 4; r++)
      creg[a][r] = c0[((v * 2 + a) * 16 + q * 4 + r) * 1024 + ks + li];
  float bs[4];
#pragma unroll
  for (int g = 0; g < 4; g++) bs[g] = bias[(g << 10) + ks + li];
  __syncthreads();  // Wht resident

  for (int t = 0; t < 512; t++) {
    // wait until every slice of h_t is published (flags[s] >= t)
    for (;;) {
      int f = __hip_atomic_load(&flags[l], __ATOMIC_RELAXED, __HIP_MEMORY_SCOPE_AGENT);
      if (__all(f >= t)) break;
      __builtin_amdgcn_s_sleep(1);
    }
    __builtin_amdgcn_fence(__ATOMIC_ACQUIRE, "workgroup");  // no load hoisting above poll

    // stage this wg's xproj slice for step t (consumed after the K-loop barrier)
    const _Float16* xpt = xproj + (long)t * 262144;
#pragma unroll
    for (int i = 0; i < 4; i++) {
      int c = i * 128 + tid;
      int g = c >> 7, b = (c >> 1) & 63, hh = c & 1;
      gll16(xpt + (long)b * 4096 + (g << 10) + ks + hh * 8, sXp + (c - l) * 8);
    }

    // K-loop: gates(64x64 slice) += h_t @ Wh_slice
    const _Float16* h0p = hbuf + (long)t * 65536 + (long)((v * 2 + 0) * 16 + li) * 1024 + q * 8;
    const _Float16* h1p = hbuf + (long)t * 65536 + (long)((v * 2 + 1) * 16 + li) * 1024 + q * 8;
    floatx4 acc[2][4] = {};
    half8 ap0[4], ap1[4];
#pragma unroll
    for (int p = 0; p < 4; p++) {
      ap0[p] = *(const half8*)(h0p + p * 32);
      ap1[p] = *(const half8*)(h1p + p * 32);
    }
    const half8* pW = (const half8*)sW;
#pragma unroll
    for (int kk = 0; kk < 32; kk++) {
      half8 a0 = ap0[kk & 3], a1 = ap1[kk & 3];
#pragma unroll
      for (int g = 0; g < 4; g++) {
        half8 b = pW[((g * 32 + kk) << 6) + l];
        acc[0][g] = __builtin_amdgcn_mfma_f32_16x16x32_f16(a0, b, acc[0][g], 0, 0, 0);
        acc[1][g] = __builtin_amdgcn_mfma_f32_16x16x32_f16(a1, b, acc[1][g], 0, 0, 0);
      }
      if (kk < 28) {
        ap0[kk & 3] = *(const half8*)(h0p + (kk + 4) * 32);
        ap1[kk & 3] = *(const half8*)(h1p + (kk + 4) * 32);
      }
    }
    __syncthreads();  // sXp staged (vmcnt drained), both waves done

    // epilogue: lane-local i,f,g,o for each (b, kc)
    _Float16* hnext = hbuf + (long)(t + 1) * 65536;
#pragma unroll
    for (int a = 0; a < 2; a++) {
#pragma unroll
      for (int r = 0; r < 4; r++) {
        int b = (v * 2 + a) * 16 + q * 4 + r;
        float gi = acc[a][0][r] + (float)sXp[((0 << 7) + b * 2 + (li >> 3)) * 8 + (li & 7)] + bs[0];
        float gf = acc[a][1][r] + (float)sXp[((1 << 7) + b * 2 + (li >> 3)) * 8 + (li & 7)] + bs[1];
        float gg = acc[a][2][r] + (float)sXp[((2 << 7) + b * 2 + (li >> 3)) * 8 + (li & 7)] + bs[2];
        float go = acc[a][3][r] + (float)sXp[((3 << 7) + b * 2 + (li >> 3)) * 8 + (li & 7)] + bs[3];
        float cN = sigm(gf) * creg[a][r] + sigm(gi) * tanhfast(gg);
        creg[a][r] = cN;
        float hN = sigm(go) * tanhfast(cN);
        // agent-scope store: write through past the non-coherent per-XCD L2
        unsigned short hu = __builtin_bit_cast(unsigned short, (_Float16)hN);
        __hip_atomic_store((unsigned short*)hnext + (long)b * 1024 + ks + li, hu,
                           __ATOMIC_RELAXED, __HIP_MEMORY_SCOPE_AGENT);
        out[131072 + (long)b * 524288 + (long)t * 1024 + ks + li] = hN;  // ys[b][t][k]
        if (t == 511) {
          out[(long)b * 1024 + ks + li] = cN;          // cT
          out[65536 + (long)b * 1024 + ks + li] = hN;  // hT
        }
      }
    }
    __builtin_amdgcn_s_waitcnt(0);  // all h stores globally acked
    __syncthreads();
    if (tid == 0)
      __hip_atomic_store(&flags[wgid], t + 1, __ATOMIC_RELAXED, __HIP_MEMORY_SCOPE_AGENT);
  }
}

// ---------------- host ----------------
extern "C" void kernel_launch(void* const* d_in, const int* in_sizes, int n_in,
                              void* d_out, int out_size, void* d_ws, size_t ws_size,
                              hipStream_t stream) {
  const float* c0 = (const float*)d_in[0];
  const float* h0 = (const float*)d_in[1];
  const float* xs = (const float*)d_in[2];
  const float* Wx = (const float*)d_in[3];
  const float* Wh = (const float*)d_in[4];
  const float* bias = (const float*)d_in[5];
  float* out = (float*)d_out;

  char* ws = (char*)d_ws;
  size_t off = 0;
  _Float16* xs16 = (_Float16*)(ws + off); off += 67108864;    // 32768x1024 f16
  _Float16* wxt  = (_Float16*)(ws + off); off += 8388608;     // 4096x1024 f16
  _Float16* wht  = (_Float16*)(ws + off); off += 8388608;     // 4096x1024 f16
  _Float16* xprj = (_Float16*)(ws + off); off += 268435456;   // 32768x4096 f16
  _Float16* hbuf = (_Float16*)(ws + off); off += 67239936;    // 513x64x1024 f16
  int* flags     = (int*)(ws + off);      off += 256;
  if (ws_size < off) return;  // insufficient scratch: fail loudly (absmax blows up)

  prep_ew<<<16417, 256, 0, stream>>>(xs, h0, xs16, hbuf, flags);
  transpose_k<<<dim3(128, 32), dim3(32, 8), 0, stream>>>(Wx, wxt);
  transpose_k<<<dim3(128, 32), dim3(32, 8), 0, stream>>>(Wh, wht);
  gemm1<<<dim3(32, 256), 256, 0, stream>>>(xs16, wxt, xprj);
  rec<<<64, 128, 0, stream>>>(xprj, wht, bias, c0, hbuf, flags, out);
}

// Round 2
// 6043.132 us; speedup vs baseline: 1.0347x; 1.0347x over previous
//
#include <hip/hip_runtime.h>

// LSTM: B=64, T=512, D=1024, H=1024.
//   prep_ew:   xs f32->f16, h0 f32->f16 (hbuf slot 0), zero 256 flags
//   transpose: Wx,Wh [1024x4096] f32 -> [4096x1024] f16 (B^T, k-contiguous)
//   gemm1:     xproj = xs@Wx, f16 MFMA 128x128 tiles, rows t*64+b, f16
//   rec:       persistent 64 wgs x 256 thr (1/CU), Wh^T slice in LDS,
//              4 waves fully decoupled (no intra-step barriers), per-WAVE
//              flags, flag publish before ys stores, lane-local epilogue.

typedef _Float16 half8 __attribute__((ext_vector_type(8)));
typedef float floatx4 __attribute__((ext_vector_type(4)));

__device__ __forceinline__ void gll16(const void* g, void* l) {
  __builtin_amdgcn_global_load_lds(
      (const __attribute__((address_space(1))) unsigned int*)g,
      (__attribute__((address_space(3))) unsigned int*)l, 16, 0, 0);
}

__device__ __forceinline__ float sigm(float x) { return 1.f / (1.f + __expf(-x)); }
__device__ __forceinline__ float tanhfast(float x) { return 1.f - 2.f / (__expf(2.f * x) + 1.f); }

// ---------------- prep: convert xs, h0; zero flags ----------------
__global__ void prep_ew(const float* __restrict__ xs, const float* __restrict__ h0,
                        _Float16* __restrict__ xs16, _Float16* __restrict__ hb0,
                        int* __restrict__ flags) {
  long gid = (long)blockIdx.x * blockDim.x + threadIdx.x;
  if (gid < 4194304) {
    const float4* p = (const float4*)xs + gid * 2;
    float4 u = p[0], w = p[1];
    half8 o;
    o[0] = (_Float16)u.x; o[1] = (_Float16)u.y; o[2] = (_Float16)u.z; o[3] = (_Float16)u.w;
    o[4] = (_Float16)w.x; o[5] = (_Float16)w.y; o[6] = (_Float16)w.z; o[7] = (_Float16)w.w;
    *(half8*)(xs16 + gid * 8) = o;
  } else if (gid < 4202496) {
    long j = gid - 4194304;
    const float4* p = (const float4*)h0 + j * 2;
    float4 u = p[0], w = p[1];
    half8 o;
    o[0] = (_Float16)u.x; o[1] = (_Float16)u.y; o[2] = (_Float16)u.z; o[3] = (_Float16)u.w;
    o[4] = (_Float16)w.x; o[5] = (_Float16)w.y; o[6] = (_Float16)w.z; o[7] = (_Float16)w.w;
    *(half8*)(hb0 + j * 8) = o;
  } else if (gid < 4202752) {
    flags[gid - 4202496] = 0;
  }
}

// ---------------- transpose [1024][4096] f32 -> [4096][1024] f16 ----------------
__global__ void transpose_k(const float* __restrict__ in, _Float16* __restrict__ outp) {
  __shared__ float s[32][33];
  int bx = blockIdx.x * 32, by = blockIdx.y * 32;
  int tx = threadIdx.x, ty = threadIdx.y;
#pragma unroll
  for (int k = 0; k < 32; k += 8)
    s[ty + k][tx] = in[(long)(by + ty + k) * 4096 + bx + tx];
  __syncthreads();
#pragma unroll
  for (int k = 0; k < 32; k += 8)
    outp[(long)(bx + ty + k) * 1024 + by + tx] = (_Float16)s[tx][ty + k];
}

// ---------------- gemm1: xproj[t*64+b][j] = sum_k xs16[b*512+t][k] * Wxt[j][k] ----------------
__global__ __launch_bounds__(256) void gemm1(const _Float16* __restrict__ A,
                                             const _Float16* __restrict__ Bt,
                                             _Float16* __restrict__ C) {
  __shared__ _Float16 sA[4096], sB[4096];
  const int tid = threadIdx.x;
  const int w = tid >> 6, l = tid & 63, li = l & 15, q = l >> 4;
  const int wr = w >> 1, wc = w & 1;
  const int m0 = blockIdx.y * 128, n0 = blockIdx.x * 128;
  floatx4 acc[4][4] = {};
  const _Float16* gA0 = A + (long)(m0 + (w * 16 + li)) * 1024 + q * 8;
  const _Float16* gA1 = A + (long)(m0 + ((4 + w) * 16 + li)) * 1024 + q * 8;
  const _Float16* gB0 = Bt + (long)(n0 + (w * 16 + li)) * 1024 + q * 8;
  const _Float16* gB1 = Bt + (long)(n0 + ((4 + w) * 16 + li)) * 1024 + q * 8;
  _Float16* lA0 = sA + (w * 64) * 8;
  _Float16* lA1 = sA + (256 + w * 64) * 8;
  _Float16* lB0 = sB + (w * 64) * 8;
  _Float16* lB1 = sB + (256 + w * 64) * 8;
  for (int k0 = 0; k0 < 1024; k0 += 32) {
    __syncthreads();
    gll16(gA0 + k0, lA0);
    gll16(gA1 + k0, lA1);
    gll16(gB0 + k0, lB0);
    gll16(gB1 + k0, lB1);
    __syncthreads();
    half8 af[4], bf[4];
    const half8* pA = (const half8*)sA;
    const half8* pB = (const half8*)sB;
#pragma unroll
    for (int i = 0; i < 4; i++) af[i] = pA[(wr * 4 + i) * 64 + l];
#pragma unroll
    for (int j = 0; j < 4; j++) bf[j] = pB[(wc * 4 + j) * 64 + l];
#pragma unroll
    for (int i = 0; i < 4; i++)
#pragma unroll
      for (int j = 0; j < 4; j++)
        acc[i][j] = __builtin_amdgcn_mfma_f32_16x16x32_f16(af[i], bf[j], acc[i][j], 0, 0, 0);
  }
#pragma unroll
  for (int i = 0; i < 4; i++) {
#pragma unroll
    for (int r = 0; r < 4; r++) {
      int m = m0 + wr * 64 + i * 16 + q * 4 + r;
      long orow = (long)(m & 511) * 64 + (m >> 9);
#pragma unroll
      for (int j = 0; j < 4; j++) {
        int gn = n0 + wc * 64 + j * 16 + li;
        C[orow * 4096 + gn] = (_Float16)acc[i][j][r];
      }
    }
  }
}

// ---------------- rec: persistent scan, wave-decoupled ----------------
// 64 wgs x 256 thr. wg w owns h-cols [w*16, w*16+16). Wave v owns batches
// [16v,16v+16), all 4 gates -> lane-local epilogue. Per-WAVE flags[4*wg+v].
__global__ __launch_bounds__(256, 1) void rec(const _Float16* __restrict__ xproj,
                                              const _Float16* __restrict__ Wht,
                                              const float* __restrict__ bias,
                                              const float* __restrict__ c0,
                                              _Float16* __restrict__ hbuf,
                                              int* __restrict__ flags,
                                              float* __restrict__ out) {
  __shared__ _Float16 sW[65536];  // [g(4)][kk(32)][lane(64)][8] = 128 KB
  const int tid = threadIdx.x;
  const int wgid = blockIdx.x;  // 0..63
  const int v = tid >> 6;       // wave 0..3
  const int l = tid & 63, li = l & 15, q = l >> 4;
  const int ks = wgid * 16;

  // stage Wh^T slice into LDS once: 8192 x 16B chunks
#pragma unroll 4
  for (int i = 0; i < 32; i++) {
    int c = i * 256 + tid;
    int g = c >> 11, kk = (c >> 6) & 31;
    int cli = c & 15, cq = (c >> 4) & 3;
    gll16(Wht + (long)((g << 10) + ks + cli) * 1024 + kk * 32 + cq * 8,
          sW + (long)(c - l) * 8);
  }
  float creg[4];
#pragma unroll
  for (int r = 0; r < 4; r++)
    creg[r] = c0[(long)(v * 16 + q * 4 + r) * 1024 + ks + li];
  float bs[4];
#pragma unroll
  for (int g = 0; g < 4; g++) bs[g] = bias[(g << 10) + ks + li];
  __syncthreads();  // sW resident; last barrier in the kernel

  const half8* pW = (const half8*)sW;
  const int fbase = 4 * l;  // lane l audits wg l's 4 wave-flags

  for (int t = 0; t < 512; t++) {
    // prefetch this lane's 16 xproj scalars (read-only, hidden behind poll)
    const _Float16* xpt = xproj + (long)t * 262144 + ks + li;
    _Float16 xv[4][4];
#pragma unroll
    for (int g = 0; g < 4; g++)
#pragma unroll
      for (int r = 0; r < 4; r++)
        xv[g][r] = xpt[(long)(v * 16 + q * 4 + r) * 4096 + (g << 10)];

    // one-shot poll of all 256 wave-flags
    for (;;) {
      int f0 = __hip_atomic_load(&flags[fbase + 0], __ATOMIC_RELAXED, __HIP_MEMORY_SCOPE_AGENT);
      int f1 = __hip_atomic_load(&flags[fbase + 1], __ATOMIC_RELAXED, __HIP_MEMORY_SCOPE_AGENT);
      int f2 = __hip_atomic_load(&flags[fbase + 2], __ATOMIC_RELAXED, __HIP_MEMORY_SCOPE_AGENT);
      int f3 = __hip_atomic_load(&flags[fbase + 3], __ATOMIC_RELAXED, __HIP_MEMORY_SCOPE_AGENT);
      int fm = min(min(f0, f1), min(f2, f3));
      if (__all(fm >= t)) break;
      __builtin_amdgcn_s_sleep(1);
    }
    __builtin_amdgcn_fence(__ATOMIC_ACQUIRE, "workgroup");  // no hoisting of h loads

    // K-loop: acc[g] += h_t[16v..16v+16][:] @ Wh[:, g*1024+ks..+16]
    const _Float16* hrow = hbuf + (long)t * 65536 + (long)(v * 16 + li) * 1024 + q * 8;
    floatx4 acc[4] = {};
    half8 ap[8];
#pragma unroll
    for (int p = 0; p < 8; p++) ap[p] = *(const half8*)(hrow + p * 32);
#pragma unroll
    for (int kk = 0; kk < 32; kk++) {
      half8 a = ap[kk & 7];
#pragma unroll
      for (int g = 0; g < 4; g++)
        acc[g] = __builtin_amdgcn_mfma_f32_16x16x32_f16(a, pW[((g * 32 + kk) << 6) + l], acc[g], 0, 0, 0);
      if (kk < 24) ap[kk & 7] = *(const half8*)(hrow + (kk + 8) * 32);
    }

    // epilogue: lane-local gates for (b = 16v+q*4+r, col ks+li)
    _Float16* hnext = hbuf + (long)(t + 1) * 65536;
    float hval[4], cval[4];
#pragma unroll
    for (int r = 0; r < 4; r++) {
      float gi = acc[0][r] + (float)xv[0][r] + bs[0];
      float gf = acc[1][r] + (float)xv[1][r] + bs[1];
      float gg = acc[2][r] + (float)xv[2][r] + bs[2];
      float go = acc[3][r] + (float)xv[3][r] + bs[3];
      float cN = sigm(gf) * creg[r] + sigm(gi) * tanhfast(gg);
      creg[r] = cN;
      cval[r] = cN;
      float hN = sigm(go) * tanhfast(cN);
      hval[r] = hN;
      int b = v * 16 + q * 4 + r;
      unsigned short hu = __builtin_bit_cast(unsigned short, (_Float16)hN);
      __hip_atomic_store((unsigned short*)hnext + (long)b * 1024 + ks + li, hu,
                         __ATOMIC_RELAXED, __HIP_MEMORY_SCOPE_AGENT);
    }
    __builtin_amdgcn_s_waitcnt(0);  // drains ONLY the 4 h stores (rest consumed)
    if (l == 0)
      __hip_atomic_store(&flags[4 * wgid + v], t + 1, __ATOMIC_RELAXED, __HIP_MEMORY_SCOPE_AGENT);

    // slow ys (+ final cT/hT) stores AFTER publishing — off the critical path
#pragma unroll
    for (int r = 0; r < 4; r++) {
      int b = v * 16 + q * 4 + r;
      out[131072 + (long)b * 524288 + (long)t * 1024 + ks + li] = hval[r];
      if (t == 511) {
        out[(long)b * 1024 + ks + li] = cval[r];
        out[65536 + (long)b * 1024 + ks + li] = hval[r];
      }
    }
  }
}

// ---------------- host ----------------
extern "C" void kernel_launch(void* const* d_in, const int* in_sizes, int n_in,
                              void* d_out, int out_size, void* d_ws, size_t ws_size,
                              hipStream_t stream) {
  const float* c0 = (const float*)d_in[0];
  const float* h0 = (const float*)d_in[1];
  const float* xs = (const float*)d_in[2];
  const float* Wx = (const float*)d_in[3];
  const float* Wh = (const float*)d_in[4];
  const float* bias = (const float*)d_in[5];
  float* out = (float*)d_out;

  char* ws = (char*)d_ws;
  size_t off = 0;
  _Float16* xs16 = (_Float16*)(ws + off); off += 67108864;    // 32768x1024 f16
  _Float16* wxt  = (_Float16*)(ws + off); off += 8388608;     // 4096x1024 f16
  _Float16* wht  = (_Float16*)(ws + off); off += 8388608;     // 4096x1024 f16
  _Float16* xprj = (_Float16*)(ws + off); off += 268435456;   // 32768x4096 f16
  _Float16* hbuf = (_Float16*)(ws + off); off += 67239936;    // 513x64x1024 f16
  int* flags     = (int*)(ws + off);      off += 1024;        // 256 wave-flags
  if (ws_size < off) return;

  prep_ew<<<16417, 256, 0, stream>>>(xs, h0, xs16, hbuf, flags);
  transpose_k<<<dim3(128, 32), dim3(32, 8), 0, stream>>>(Wx, wxt);
  transpose_k<<<dim3(128, 32), dim3(32, 8), 0, stream>>>(Wh, wht);
  gemm1<<<dim3(32, 256), 256, 0, stream>>>(xs16, wxt, xprj);
  rec<<<64, 256, 0, stream>>>(xprj, wht, bias, c0, hbuf, flags, out);
}